// Round 7
// baseline (1942.956 us; speedup 1.0000x reference)
//
#include <hip/hip_runtime.h>
#include <cstddef>

#define LOG2E 1.4426950408889634f
#define LN2   0.6931471805599453f

typedef float    f32x2 __attribute__((ext_vector_type(2)));
typedef float    f32x4 __attribute__((ext_vector_type(4)));
typedef _Float16 half8 __attribute__((ext_vector_type(8)));

constexpr int K_    = 256;
constexpr int T_    = 2048;
constexpr int DMAX_ = 64;
constexpr int B_    = 16;

__device__ __forceinline__ float fexp2(float x) { return __builtin_amdgcn_exp2f(x); }
__device__ __forceinline__ float flog2(float x) { return __builtin_amdgcn_logf(x); }
__device__ __forceinline__ float frcp (float x) { return __builtin_amdgcn_rcpf(x); }

// cross-half (lane ^ 32) exchange via v_permlane32_swap_b32 (VALU).
// fmax/sum over {r.x, r.y} is correct under either HW swap convention.
__device__ __forceinline__ f32x2 xchg32(float x) {
    float a = x, b;
    asm("v_mov_b32 %1, %2\n\t"
        "s_nop 1\n\t"
        "v_permlane32_swap_b32 %0, %1"
        : "+v"(a), "=&v"(b)
        : "v"(x));
    return (f32x2){a, b};
}
// 16-row pair exchange via v_permlane16_swap_b32 (VALU), same argument.
__device__ __forceinline__ f32x2 xchg16(float x) {
    float a = x, b;
    asm("v_mov_b32 %1, %2\n\t"
        "s_nop 1\n\t"
        "v_permlane16_swap_b32 %0, %1"
        : "+v"(a), "=&v"(b)
        : "v"(x));
    return (f32x2){a, b};
}

// max-reduce across a 16-lane row via DPP row_ror (VALU, no LDS pipe).
template<int CTRL>
__device__ __forceinline__ float dpp_maxf(float x) {
    int m = __builtin_amdgcn_update_dpp(0, __builtin_bit_cast(int, x), CTRL, 0xF, 0xF, true);
    return fmaxf(x, __builtin_bit_cast(float, m));
}

// 256 threads = 4 waves, 1 wave/SIMD. LDS-pipe-minimal design:
// lane l of wave w owns column j = tid = 64w + l ENTIRELY (all 64 ages,
// 32 pairs v[i] = {age 1+i, age 33+i}).
//   -> duration dot, shift, rescale, age handoff: fully lane-local (NO
//      cross-lane ops on the recurrence at all).
//   -> per-step LDS = 1 ds_write_b16 + 8 ds_read_b128 per wave (fragments
//      SHARED by the wave's 4 MFMA output tiles): 36 LDS instr/CU/step vs
//      round-4's 72 / round-5's 145 -- the measured bottleneck pipe.
//   -> MFMA: 4 tiles x 8 kc = 32 MFMAs/wave; output select d[g].x, g=l>>4
//      (3 cndmask). B-frags = 128 VGPR; ~330 VGPR total, fine at 1 wave/SIMD.
// Anchor machinery at half rate (even: wave max + lds_red[4] write; odd:
// 16B broadcast read + reduce). One pinned barrier/step; depth-3 prefetch.
__global__ __launch_bounds__(256)
__attribute__((amdgpu_waves_per_eu(1, 1)))
void hsmm_fwd_kernel(const float* __restrict__ logB,   // [B,T,K]
                     const float* __restrict__ pi,     // [K]
                     const float* __restrict__ A,      // [K,K]
                     const float* __restrict__ D,      // [K,DMAX]
                     float* __restrict__ out)          // [16] loglik ++ [B,T,K] alphas
{
    const int b    = blockIdx.x;
    const int tid  = threadIdx.x;
    const int w    = tid >> 6;                 // wave 0..3
    const int lane = tid & 63;
    const int g    = lane >> 4;                // fragment row-group 0..3
    const int j    = tid;                      // owned column 0..255

    alignas(16) __shared__ _Float16 lds_ph[2][K_];    // p f16, ping-pong by t&1
    alignas(16) __shared__ float    lds_red[4];       // per-wave max a_in

    // ---- init: B-fragments (P = exp(A_logits), f16, MFMA B-layout) ----
    // tile tau covers cols 64w + 16*tau + (lane&15); lane holds B rows
    // k = kc*32 + g*8 + i.
    half8 Bf[4][8];
    {
        const int kbase = g * 8;
        #pragma unroll
        for (int tau = 0; tau < 4; ++tau) {
            const int col = (w << 6) + (tau << 4) + (lane & 15);
            #pragma unroll
            for (int kc = 0; kc < 8; ++kc) {
                #pragma unroll
                for (int i = 0; i < 8; ++i)
                    Bf[tau][kc][i] = (_Float16)fexp2(
                        A[(size_t)(kc * 32 + kbase + i) * K_ + col] * LOG2E);
            }
        }
    }
    // pD pairs: pDf[i] = {pD(age 1+i), pD(age 33+i)}, i = 0..31
    f32x2 pDf[32];
    {
        const float* Dj = D + (size_t)j * DMAX_;
        #pragma unroll
        for (int i = 0; i < 32; ++i)
            pDf[i] = (f32x2){ fexp2(Dj[i] * LOG2E), fexp2(Dj[32 + i] * LOG2E) };
    }

    // v[i] = values at ages {1+i, 33+i} of column j (all lane-local)
    f32x2 v[32];
    #pragma unroll
    for (int i = 0; i < 32; ++i) v[i] = (f32x2){0.0f, 0.0f};
    v[0].x = 1.0f;                      // age-1 holds pi mass (anchor = pi)
    float mcol     = pi[j] * LOG2E;     // column anchor (base-2)
    float cumb     = 0.0f;
    float m_anchor = 0.0f;              // block anchor (lag 2-3)

    if (tid < 4) lds_red[tid] = 0.0f;
    __syncthreads();

    const float* lb = logB + (size_t)b * T_ * K_ + j;
    float*       ao = out + 16 + (size_t)b * T_ * K_ + j;

    // depth-3 prefetch ring for the per-step emission
    float bld0 = lb[0];
    float bld1 = lb[K_];
    float bld2 = lb[2 * K_];
    int   ldoff = 3 * K_;
    int   aoff  = 0;

    // static even/odd step body (EVEN: anchor-feed write; ODD: anchor update)
    auto body = [&](int t, int s, bool even) __attribute__((always_inline)) {
        cumb = fmaf(bld0, LOG2E, cumb);

        const float argh = 0.5f * (cumb + mcol - m_anchor);
        const float ea   = fminf(fexp2(argh),  1.8e19f);
        const float ga   = fminf(fexp2(-argh), 1.8e19f);
        const float mac  = m_anchor - cumb;

        // ---- duration dot: 32 pk_fma, 4 chains, fully lane-local ----
        f32x2 s0 = {0.f,0.f}, s1 = {0.f,0.f}, s2 = {0.f,0.f}, s3 = {0.f,0.f};
        #pragma unroll
        for (int i = 0; i < 32; i += 4) {
            s0 = __builtin_elementwise_fma(v[i + 0], pDf[i + 0], s0);
            s1 = __builtin_elementwise_fma(v[i + 1], pDf[i + 1], s1);
            s2 = __builtin_elementwise_fma(v[i + 2], pDf[i + 2], s2);
            s3 = __builtin_elementwise_fma(v[i + 3], pDf[i + 3], s3);
        }
        f32x2 sp = (s0 + s1) + (s2 + s3);
        float S  = sp.x + sp.y;                 // full sum, no cross-lane

        float p = fminf(S * ea * ea, 60000.0f); // f16-overflow clamp
        lds_ph[s][j] = (_Float16)p;             // every lane: own column

        // ---- the ONE barrier: pinned so no LDS op crosses it ----
        asm volatile("s_waitcnt lgkmcnt(0)" ::: "memory");
        __builtin_amdgcn_sched_barrier(0);
        __builtin_amdgcn_s_barrier();
        __builtin_amdgcn_sched_barrier(0);

        // globals: prefetch t+3 (in flight across barriers) + alpha store
        bld0 = bld1; bld1 = bld2;
        bld2 = lb[ldoff];
        ldoff += (ldoff < (T_ - 1) * K_) ? K_ : 0;
        ao[aoff] = (cumb + mcol + flog2(S)) * LN2;
        aoff += K_;

        f32x4 r;
        if (!even)      // hoisted anchor read: 16B broadcast, overlaps MFMA
            r = *(const f32x4*)lds_red;

        // ---- MFMA matvec: 8 shared A-fragments, 4 tiles, 32 MFMAs ----
        const _Float16* pb = lds_ph[s];
        const int kbase = g * 8;
        half8 af[8];
        #pragma unroll
        for (int kc = 0; kc < 8; ++kc)
            af[kc] = *(const half8*)(pb + kc * 32 + kbase);
        const f32x4 z = {0.f,0.f,0.f,0.f};
        f32x4 d0 = z, d1 = z, d2 = z, d3 = z;
        #pragma unroll
        for (int kc = 0; kc < 8; ++kc) {
            d0 = __builtin_amdgcn_mfma_f32_16x16x32_f16(af[kc], Bf[0][kc], d0, 0, 0, 0);
            d1 = __builtin_amdgcn_mfma_f32_16x16x32_f16(af[kc], Bf[1][kc], d1, 0, 0, 0);
            d2 = __builtin_amdgcn_mfma_f32_16x16x32_f16(af[kc], Bf[2][kc], d2, 0, 0, 0);
            d3 = __builtin_amdgcn_mfma_f32_16x16x32_f16(af[kc], Bf[3][kc], d3, 0, 0, 0);
        }
        // own column = tile g, col lane&15 (all D rows identical): 3 cndmask
        float mySmv = (g == 0) ? d0.x : (g == 1) ? d1.x : (g == 2) ? d2.x : d3.x;

        float m_next = 0.0f;
        if (even) {
            // anchor feed: full-wave max (64 cols) via DPP ror + permlane
            float mx = mySmv;
            mx = dpp_maxf<0x121>(mx);   // ror:1
            mx = dpp_maxf<0x122>(mx);   // ror:2
            mx = dpp_maxf<0x124>(mx);   // ror:4
            mx = dpp_maxf<0x128>(mx);   // ror:8
            f32x2 h16 = xchg16(mx); mx = fmaxf(h16.x, h16.y);
            f32x2 h32 = xchg32(mx); mx = fmaxf(h32.x, h32.y);
            if (lane == 0) lds_red[w] = m_anchor + flog2(fmaxf(mx, 1e-30f));
        } else {
            m_next = fmaxf(fmaxf(r.x, r.y), fmaxf(r.z, r.w));
        }

        // ---- insert + PAIR shift/rescale: 31 pk_mul + fixups, lane-local ----
        float nv0 = mySmv * ga * ga;            // exp2(vnew - mcol)
        float rsc = frcp(fmaxf(nv0, 1.0f));     // exp2(mcol - mnew)
        float nv  = fminf(nv0, 1.0f);           // exp2(vnew - mnew)
        mcol = fmaxf(mcol, mac + flog2(mySmv)); // exact-log anchor update

        float p31 = v[31].x;                    // old age 32
        f32x2 rp = { rsc, rsc };
        #pragma unroll
        for (int k = 31; k >= 1; --k)
            v[k] = v[k - 1] * rp;               // ages +1, both halves
        v[0].y = p31 * rsc;                     // age 33 <- old age 32
        v[0].x = nv;                            // age 1  <- insert

        if (!even && t + 1 < T_) m_anchor = m_next;  // keep final anchor for loglik
    };

    for (int t = 0; t < T_; t += 2) {
        body(t,     0, true );
        body(t + 1, 1, false);
    }

    // ---- loglik: lds_ph[1] holds f16 exp2(alpha_{T-1} - m_anchor) ----
    if (tid < 64) {
        const _Float16* lp = lds_ph[(T_ - 1) & 1];
        float sf = (float)lp[tid] + (float)lp[tid + 64]
                 + (float)lp[tid + 128] + (float)lp[tid + 192];
        #pragma unroll
        for (int off = 1; off < 64; off <<= 1)
            sf += __shfl_xor(sf, off, 64);
        if (tid == 0) out[b] = (m_anchor + flog2(sf)) * LN2;
    }
}

extern "C" void kernel_launch(void* const* d_in, const int* in_sizes, int n_in,
                              void* d_out, int out_size, void* d_ws, size_t ws_size,
                              hipStream_t stream) {
    const float* logB = (const float*)d_in[0];   // [16,2048,256]
    const float* pi   = (const float*)d_in[1];   // [256]
    const float* A    = (const float*)d_in[2];   // [256,256]
    const float* D    = (const float*)d_in[3];   // [256,64]
    float* out = (float*)d_out;
    (void)in_sizes; (void)n_in; (void)d_ws; (void)ws_size; (void)out_size;

    hipLaunchKernelGGL(hsmm_fwd_kernel, dim3(B_), dim3(256), 0, stream,
                       logB, pi, A, D, out);
}